// Round 2
// baseline (281.438 us; speedup 1.0000x reference)
//
#include <hip/hip_runtime.h>
#include <float.h>

// PQHead forward: out[b, m*6+d] = codebooks[m, argmax_k dot(x[b,m,:], cb[m,k,:]), d]
// (straight-through estimator: forward value of quant is exactly `discrete`)
//
// R8: amortize the block prologue. R7 post-mortem: VALU-busy TIME is ~46us in
// both R6/R7; only stalls differ. R6's remaining stall is dominated by the
// per-block serial cold start (12 cb float4 loads + stage-0 x loads + barrier
// ~600-900cy) over only 2 stages of work, plus per-block tails.
//  - BROWS 16 -> 64: 8 stages per block, prologue amortized 4x.
//  - Grid 4096 -> 1024 blocks; 24 KiB LDS -> 4 blocks/CU, ALL blocks
//    co-resident (one dispatch round, uniform load).
//  - Everything else is the proven R6 structure: LDS x broadcast staging,
//    cross-stage register prefetch, v_pk_fma dots, DPP quad merge, fp64
//    near-tie fallback, batched gathers behind sched_barrier, float2 stores.

typedef float v2f __attribute__((ext_vector_type(2)));

#define BATCH 32768
#define DIM   768
#define K_CB  32
#define D_SUB 6
#define BROWS 64               // rows per block
#define RSTG  8                // rows per LDS stage
#define NSTG  (BROWS/RSTG)     // 8 stages
#define HALFF 384              // floats per half row (64 m * 6)
#define STGF  (RSTG*HALFF)     // 3072 floats = 12 KiB per buffer

#define DPP_XOR1 0xB1          // quad_perm [1,0,3,2]
#define DPP_XOR2 0x4E          // quad_perm [2,3,0,1]

template<int CTRL>
__device__ __forceinline__ float dppf(float v) {
    return __int_as_float(__builtin_amdgcn_update_dpp(
        0, __float_as_int(v), CTRL, 0xF, 0xF, true));
}
template<int CTRL>
__device__ __forceinline__ int dppi(int v) {
    return __builtin_amdgcn_update_dpp(0, v, CTRL, 0xF, 0xF, true);
}

__global__ __launch_bounds__(256, 4)
void pq_head_kernel(const float* __restrict__ x,
                    const float* __restrict__ cb,
                    float* __restrict__ out) {
    __shared__ float xs[2][STGF];   // 24 KiB double buffer

    const int t     = threadIdx.x;
    const int kq    = t & 3;        // k-quarter (lane within quad)
    const int mloc  = t >> 2;       // 0..63
    const int mhalf = blockIdx.y;   // 0/1
    const int m     = mhalf * 64 + mloc;
    const int b0    = blockIdx.x * BROWS;

    // Load this lane's 8 codebook rows (48 floats, 192-B aligned) and pack
    // code-pairs into v2f: cpk[p][e] = (cb[2p][e], cb[2p+1][e]).
    v2f cpk[4][D_SUB];
    {
        float cc[48];
        const float4* cb4 = reinterpret_cast<const float4*>(
            cb + ((size_t)m * K_CB + (size_t)kq * 8) * D_SUB);
        #pragma unroll
        for (int i = 0; i < 12; ++i) {
            float4 v = cb4[i];
            cc[4*i+0]=v.x; cc[4*i+1]=v.y; cc[4*i+2]=v.z; cc[4*i+3]=v.w;
        }
        #pragma unroll
        for (int p = 0; p < 4; ++p)
            #pragma unroll
            for (int e = 0; e < D_SUB; ++e)
                cpk[p][e] = (v2f){cc[(2*p)*D_SUB + e], cc[(2*p+1)*D_SUB + e]};
    }

    const float* xh = x   + (size_t)mhalf * HALFF;  // half-row base
    float*       oh = out + (size_t)mhalf * HALFF;

    // Stage-invariant (row, col) for the coalesced stage load.
    int pr[3], pc[3];
    #pragma unroll
    for (int i = 0; i < 3; ++i) {
        int f = (i * 256 + t) * 4;          // float index within stage (<3072)
        pr[i] = f / HALFF;
        pc[i] = f - pr[i] * HALFF;
    }

    // Prefetch stage 0 (3 x dwordx4 per thread, fully coalesced).
    float4 pf[3];
    #pragma unroll
    for (int i = 0; i < 3; ++i)
        pf[i] = *reinterpret_cast<const float4*>(xh + (size_t)(b0 + pr[i]) * DIM + pc[i]);

    for (int s = 0; s < NSTG; ++s) {
        float* buf = xs[s & 1];
        #pragma unroll
        for (int i = 0; i < 3; ++i)
            *reinterpret_cast<float4*>(&buf[(i * 256 + t) * 4]) = pf[i];
        __syncthreads();   // writers of buf done; stage s+1 writes the OTHER buffer

        if (s + 1 < NSTG) {                 // prefetch next stage; consumer is
            int rb = b0 + (s + 1) * RSTG;   // a ds_write past this stage's compute
            #pragma unroll
            for (int i = 0; i < 3; ++i)
                pf[i] = *reinterpret_cast<const float4*>(
                    xh + (size_t)(rb + pr[i]) * DIM + pc[i]);
        }

        // ---- phase A: 8 winner computations -> kg8[] ----
        int kg8[RSTG];
        #pragma unroll
        for (int r = 0; r < RSTG; ++r) {
            const float* xr = &buf[r * HALFF + mloc * D_SUB];  // quad-broadcast
            float2 x01 = *reinterpret_cast<const float2*>(xr);
            float2 x23 = *reinterpret_cast<const float2*>(xr + 2);
            float2 x45 = *reinterpret_cast<const float2*>(xr + 4);
            float xv[6] = {x01.x, x01.y, x23.x, x23.y, x45.x, x45.y};
            v2f xxe[6];
            #pragma unroll
            for (int e = 0; e < 6; ++e) xxe[e] = (v2f){xv[e], xv[e]};

            float best1 = -FLT_MAX, best2 = -FLT_MAX;
            int   kg    = kq * 8;
            #pragma unroll
            for (int p = 0; p < 4; ++p) {
                v2f acc = cpk[p][0] * xxe[0];
                #pragma unroll
                for (int e = 1; e < 6; ++e)
                    acc = __builtin_elementwise_fma(cpk[p][e], xxe[e], acc);
                #pragma unroll
                for (int h = 0; h < 2; ++h) {         // j = 2p+h, ascending
                    float d  = h ? acc.y : acc.x;
                    bool  gt = d > best1;             // strict > => first wins
                    best2 = gt ? best1 : fmaxf(best2, d);
                    kg    = gt ? (kq * 8 + 2*p + h) : kg;
                    best1 = gt ? d : best1;
                }
            }

            // Quad butterfly via DPP (pure VALU).
            {
                float o1 = dppf<DPP_XOR1>(best1);
                float o2 = dppf<DPP_XOR1>(best2);
                int   ok = dppi<DPP_XOR1>(kg);
                bool take = (o1 > best1) || (o1 == best1 && ok < kg);
                best2 = fmaxf(fminf(best1, o1), fmaxf(best2, o2));
                kg    = take ? ok : kg;
                best1 = fmaxf(best1, o1);
            }
            {
                float o1 = dppf<DPP_XOR2>(best1);
                float o2 = dppf<DPP_XOR2>(best2);
                int   ok = dppi<DPP_XOR2>(kg);
                bool take = (o1 > best1) || (o1 == best1 && ok < kg);
                best2 = fmaxf(fminf(best1, o1), fmaxf(best2, o2));
                kg    = take ? ok : kg;
                best1 = fmaxf(best1, o1);
            }

            // Near-tie (quad-uniform, ~0.1%): exact fp64 argmax over 32 codes.
            if (best1 - best2 < 1e-5f) {
                const float* crow = cb + (size_t)m * K_CB * D_SUB;
                double db = -1e300; int dkg = 0;
                for (int k2 = 0; k2 < K_CB; ++k2) {
                    double sa = 0.0;
                    for (int e = 0; e < 6; ++e)
                        sa = fma((double)crow[k2*6+e], (double)xv[e], sa);
                    if (sa > db) { db = sa; dkg = k2; }
                }
                kg = dkg;
            }
            kg8[r] = kg;
        }

        // ---- phase B: 8 independent winner gathers (cb is L1/L2-hot) ----
        const bool act = (kq < 3);
        float2 gv[RSTG];
        if (act) {
            #pragma unroll
            for (int r = 0; r < RSTG; ++r)
                gv[r] = *(reinterpret_cast<const float2*>(
                    cb + ((size_t)m * K_CB + (size_t)kg8[r]) * D_SUB) + kq);
        }

        __builtin_amdgcn_sched_barrier(0);  // keep all gathers above all stores

        // ---- phase C: 8 coalesced float2 stores (48/64 lanes -> full lines) ----
        if (act) {
            #pragma unroll
            for (int r = 0; r < RSTG; ++r) {
                float* dst = oh + (size_t)(b0 + s * RSTG + r) * DIM + mloc * D_SUB;
                *(reinterpret_cast<float2*>(dst) + kq) = gv[r];
            }
        }
    }
}

extern "C" void kernel_launch(void* const* d_in, const int* in_sizes, int n_in,
                              void* d_out, int out_size, void* d_ws, size_t ws_size,
                              hipStream_t stream) {
    const float* x  = (const float*)d_in[0];   // (32768, 768) fp32
    const float* cb = (const float*)d_in[1];   // (128, 32, 6) fp32
    float* out = (float*)d_out;                // (32768, 768) fp32

    dim3 grid(BATCH / BROWS, 2);   // 512 x 2 = 1024 blocks
    dim3 block(256);               // 64 m x 4 k-quarters
    hipLaunchKernelGGL(pq_head_kernel, grid, block, 0, stream, x, cb, out);
}